// Round 2
// baseline (11299.061 us; speedup 1.0000x reference)
//
#include <hip/hip_runtime.h>
#include <hip/hip_fp16.h>

#define N_VAR 256
#define M_CON 512
#define BATCH 64
#define SIGMA_C 1e-6f
#define RHO_C 0.1f
#define ALPHA_C 1.6f
#define NITERS 500

// ---------------------------------------------------------------------------
// K1: transpose A [512][256] -> At [256][512] per batch
// ---------------------------------------------------------------------------
__global__ __launch_bounds__(256) void k_transpose(const float* __restrict__ A,
                                                   float* __restrict__ At) {
  __shared__ float tile[32][33];
  int b = blockIdx.z;
  int n0 = blockIdx.x * 32;
  int m0 = blockIdx.y * 32;
  const float* Ab = A + (size_t)b * (M_CON * N_VAR);
  float* Atb = At + (size_t)b * (M_CON * N_VAR);
  int tx = threadIdx.x, ty = threadIdx.y;  // (32, 8)
#pragma unroll
  for (int j = 0; j < 32; j += 8)
    tile[ty + j][tx] = Ab[(size_t)(m0 + ty + j) * N_VAR + n0 + tx];
  __syncthreads();
#pragma unroll
  for (int j = 0; j < 32; j += 8)
    Atb[(size_t)(n0 + ty + j) * M_CON + m0 + tx] = tile[tx][ty + j];
}

// ---------------------------------------------------------------------------
// K2: batched NT GEMM  C[i][j] = alpha * sum_k X[i][k]*Y[j][k]  (+ diag)
// ---------------------------------------------------------------------------
__global__ __launch_bounds__(256) void k_ntgemm(
    const float* __restrict__ X, const float* __restrict__ Y,
    float* __restrict__ C, int I, int J, int K,
    long long bsX, long long bsY, long long bsC, float alpha,
    const float* __restrict__ diagv, int tilesJ) {
  int b = blockIdx.y;
  int ti = blockIdx.x / tilesJ, tj = blockIdx.x % tilesJ;
  int i0 = ti * 128, j0 = tj * 128;
  const float* Xb = X + (size_t)b * bsX;
  const float* Yb = Y + (size_t)b * bsY;
  float* Cb = C + (size_t)b * bsC;
  __shared__ float Xs[16][128];
  __shared__ float Ys[16][128];
  int tid = threadIdx.x;
  int tx = tid & 15, ty = tid >> 4;
  float acc[8][8];
#pragma unroll
  for (int r = 0; r < 8; ++r)
#pragma unroll
    for (int c = 0; c < 8; ++c) acc[r][c] = 0.0f;

  for (int kk = 0; kk < K; kk += 16) {
#pragma unroll
    for (int v = 0; v < 2; ++v) {
      int idx = v * 256 + tid;
      int row = idx >> 2;
      int k4 = (idx & 3) * 4;
      float4 gx = *(const float4*)(Xb + (size_t)(i0 + row) * K + kk + k4);
      Xs[k4 + 0][row] = gx.x; Xs[k4 + 1][row] = gx.y;
      Xs[k4 + 2][row] = gx.z; Xs[k4 + 3][row] = gx.w;
      float4 gy = *(const float4*)(Yb + (size_t)(j0 + row) * K + kk + k4);
      Ys[k4 + 0][row] = gy.x; Ys[k4 + 1][row] = gy.y;
      Ys[k4 + 2][row] = gy.z; Ys[k4 + 3][row] = gy.w;
    }
    __syncthreads();
#pragma unroll
    for (int k = 0; k < 16; ++k) {
      float xr[8], yr[8];
      *(float4*)&xr[0] = *(float4*)&Xs[k][ty * 8];
      *(float4*)&xr[4] = *(float4*)&Xs[k][ty * 8 + 4];
      *(float4*)&yr[0] = *(float4*)&Ys[k][tx * 8];
      *(float4*)&yr[4] = *(float4*)&Ys[k][tx * 8 + 4];
#pragma unroll
      for (int r = 0; r < 8; ++r)
#pragma unroll
        for (int c = 0; c < 8; ++c) acc[r][c] += xr[r] * yr[c];
    }
    __syncthreads();
  }
#pragma unroll
  for (int r = 0; r < 8; ++r) {
    int gi = i0 + ty * 8 + r;
#pragma unroll
    for (int c = 0; c < 8; ++c) {
      int gj = j0 + tx * 8 + c;
      float val = acc[r][c] * alpha;
      if (diagv != nullptr && gi == gj) val += diagv[(size_t)b * N_VAR + gi] + SIGMA_C;
      Cb[(size_t)gi * J + gj] = val;
    }
  }
}

// ---------------------------------------------------------------------------
// K3: in-place Gauss-Jordan inversion (SPD, diag-dominant; no pivoting).
// ---------------------------------------------------------------------------
__global__ __launch_bounds__(1024) void k_invert(const float* __restrict__ Mk,
                                                 float* __restrict__ Mi) {
  int b = blockIdx.x;
  const float* src = Mk + (size_t)b * 65536;
  float* dst = Mi + (size_t)b * 65536;
  int t = threadIdx.x;
  int c = t & 255, rq = t >> 8;
  float a[64];
#pragma unroll
  for (int j = 0; j < 64; ++j) a[j] = src[j * 1024 + t];

  __shared__ float colP[2][256];
  __shared__ float rowB[2][256];

  for (int k = 0; k < 256; ++k) {
    int cur = k & 1;
    int kj = k >> 2, kq = k & 3;
    if (c == k) {
      float4* cp4 = (float4*)&colP[cur][64 * rq];
#pragma unroll
      for (int jj = 0; jj < 16; ++jj)
        cp4[jj] = make_float4(a[4 * jj], a[4 * jj + 1], a[4 * jj + 2], a[4 * jj + 3]);
    }
    __syncthreads();
    float pivinv = 1.0f / colP[cur][kj + 64 * kq];
    if (rq == kq) {
      float v = (c == k) ? pivinv : a[kj] * pivinv;
      a[kj] = v;
      rowB[cur][c] = v;
    }
    __syncthreads();
    float rb = rowB[cur][c];
    float keep = a[kj];
    const float4* cp4 = (const float4*)&colP[cur][64 * rq];
#pragma unroll
    for (int jj = 0; jj < 16; ++jj) {
      float4 cv = cp4[jj];
      a[4 * jj + 0] -= rb * cv.x;
      a[4 * jj + 1] -= rb * cv.y;
      a[4 * jj + 2] -= rb * cv.z;
      a[4 * jj + 3] -= rb * cv.w;
    }
    if (rq == kq) a[kj] = keep;
    if (c == k) {
#pragma unroll
      for (int jj = 0; jj < 16; ++jj) {
        float4 cv = cp4[jj];
        a[4 * jj + 0] = -pivinv * cv.x;
        a[4 * jj + 1] = -pivinv * cv.y;
        a[4 * jj + 2] = -pivinv * cv.z;
        a[4 * jj + 3] = -pivinv * cv.w;
      }
      if (rq == kq) a[kj] = pivinv;
    }
  }
#pragma unroll
  for (int j = 0; j < 64; ++j) dst[j * 1024 + t] = a[j];
}

// ---------------------------------------------------------------------------
// K4a: h = Minv * q  (column access via symmetry)
// ---------------------------------------------------------------------------
__global__ __launch_bounds__(256) void k_matvec_h(const float* __restrict__ Mi,
                                                  const float* __restrict__ q,
                                                  float* __restrict__ h) {
  int b = blockIdx.x, t = threadIdx.x;
  __shared__ float qs[256];
  qs[t] = q[(size_t)b * 256 + t];
  __syncthreads();
  const float* Mb = Mi + (size_t)b * 65536;
  float acc = 0.0f;
  for (int k = 0; k < 256; ++k) acc += Mb[(size_t)k * 256 + t] * qs[k];
  h[(size_t)b * 256 + t] = acc;
}

// K4b: d = A * h  via At columns
__global__ __launch_bounds__(512) void k_matvec_d(const float* __restrict__ At,
                                                  const float* __restrict__ h,
                                                  float* __restrict__ d) {
  int b = blockIdx.x, t = threadIdx.x;
  __shared__ float hs[256];
  if (t < 256) hs[t] = h[(size_t)b * 256 + t];
  __syncthreads();
  const float* Ab = At + (size_t)b * 131072;
  float acc = 0.0f;
  for (int n = 0; n < 256; ++n) acc += Ab[(size_t)n * 512 + t] * hs[n];
  d[(size_t)b * 512 + t] = acc;
}

// ---------------------------------------------------------------------------
// K5: zero the per-batch arrival counters (ws is poisoned before every call)
// ---------------------------------------------------------------------------
__global__ __launch_bounds__(256) void k_zero(int* __restrict__ ctr, int n) {
  int i = blockIdx.x * 256 + threadIdx.x;
  if (i < n) ctr[i] = 0;
}

// ---------------------------------------------------------------------------
// K6: persistent ADMM loop, register-resident G.
// 512 WGs (8 per batch) x 512 threads. WG g: batch b=g>>3, slice k=g&7 owns
// output rows m in [k*64, k*64+64). Thread t: row r=t>>3 (8 thr/row),
// col strip c(j) = q*8 + (j&7) + 64*(j>>3), q=t&7  -> 64 fp32 G values in
// VGPRs (fully unrolled). Per iter: only the 512-float w vector moves.
// Cross-WG per-batch sync: monotonic arrival counter + double-buffered w,
// all agent-scope atomics (correct under XCD L2 non-coherence).
// Co-residency: 8 waves, ~6KB LDS, ~90 VGPR -> 4 WGs/CU capacity, 1024 >= 512.
// ---------------------------------------------------------------------------
__global__ __launch_bounds__(512) void k_admm_p(
    const float* __restrict__ G, const float* __restrict__ dvec,
    const float* __restrict__ lv, const float* __restrict__ uv,
    float* __restrict__ wbuf, int* __restrict__ ctr,
    float* __restrict__ Sbuf) {
  int g = blockIdx.x;
  int b = g >> 3, k = g & 7;
  int t = threadIdx.x;
  int r = t >> 3, q = t & 7;
  int row = k * 64 + r;

  __shared__ __align__(16) float ws[512];
  __shared__ float part[64][8];
  __shared__ float zs[64], ysd[64], Ss[64], lsl[64], usl[64], dsl[64];

  const float* Gb = G + (size_t)b * 262144 + (size_t)row * 512;
  float Greg[64];
#pragma unroll
  for (int jb = 0; jb < 8; ++jb) {
    float4 g0 = *(const float4*)(Gb + q * 8 + 64 * jb);
    float4 g1 = *(const float4*)(Gb + q * 8 + 4 + 64 * jb);
    Greg[jb * 8 + 0] = g0.x; Greg[jb * 8 + 1] = g0.y;
    Greg[jb * 8 + 2] = g0.z; Greg[jb * 8 + 3] = g0.w;
    Greg[jb * 8 + 4] = g1.x; Greg[jb * 8 + 5] = g1.y;
    Greg[jb * 8 + 6] = g1.z; Greg[jb * 8 + 7] = g1.w;
  }
  if (t < 64) {
    int m = k * 64 + t;
    zs[t] = 0.0f; ysd[t] = 0.0f; Ss[t] = 0.0f;
    lsl[t] = lv[(size_t)b * 512 + m];
    usl[t] = uv[(size_t)b * 512 + m];
    dsl[t] = dvec[(size_t)b * 512 + m];
  }

  float* w0 = wbuf + (size_t)b * 512;           // parity 0
  float* w1 = wbuf + 32768 + (size_t)b * 512;   // parity 1
  int* cb = ctr + b * 32;                        // 128B-padded counter

  for (int it = 0; it < NITERS; ++it) {
    if (it == 0) {
      ws[t] = 0.0f;   // w_0 = rho*0 - 0 = 0
    } else {
      if (t == 0) {
        while (__hip_atomic_load(cb, __ATOMIC_ACQUIRE, __HIP_MEMORY_SCOPE_AGENT) < 8 * it) {}
      }
      __syncthreads();
      const float* wr = (it & 1) ? w1 : w0;
      ws[t] = __hip_atomic_load(&wr[t], __ATOMIC_RELAXED, __HIP_MEMORY_SCOPE_AGENT);
    }
    __syncthreads();

    // zt slice = G[rows] * w
    float acc = 0.0f;
    const float4* wv4 = (const float4*)ws;
#pragma unroll
    for (int jb = 0; jb < 8; ++jb) {
      float4 wa = wv4[q * 2 + 16 * jb];
      float4 wb = wv4[q * 2 + 1 + 16 * jb];
      acc += Greg[jb * 8 + 0] * wa.x + Greg[jb * 8 + 1] * wa.y +
             Greg[jb * 8 + 2] * wa.z + Greg[jb * 8 + 3] * wa.w +
             Greg[jb * 8 + 4] * wb.x + Greg[jb * 8 + 5] * wb.y +
             Greg[jb * 8 + 6] * wb.z + Greg[jb * 8 + 7] * wb.w;
    }
    part[r][q] = acc;
    __syncthreads();

    if (t < 64) {
      float wv = ws[k * 64 + t];
      Ss[t] = wv - 0.6f * Ss[t];                 // S = (1-alpha)*S + w
      float4 p0 = *(const float4*)&part[t][0];
      float4 p1 = *(const float4*)&part[t][4];
      float zt = (p0.x + p0.y + p0.z + p0.w + p1.x + p1.y + p1.z + p1.w) - dsl[t];
      float zh = ALPHA_C * zt + (1.0f - ALPHA_C) * zs[t];
      float zc = zh + ysd[t] * (1.0f / RHO_C);
      zc = fminf(fmaxf(zc, lsl[t]), usl[t]);
      ysd[t] += RHO_C * (zh - zc);
      zs[t] = zc;
      float wn = RHO_C * zc - ysd[t];            // w_{it+1}
      float* wwr = ((it + 1) & 1) ? w1 : w0;
      __hip_atomic_store(&wwr[k * 64 + t], wn, __ATOMIC_RELAXED, __HIP_MEMORY_SCOPE_AGENT);
    }
    __syncthreads();   // compiler emits s_waitcnt vmcnt(0) before barrier -> stores drained
    if (t == 0)
      __hip_atomic_fetch_add(cb, 1, __ATOMIC_RELEASE, __HIP_MEMORY_SCOPE_AGENT);
  }

  if (t < 64) Sbuf[(size_t)b * 512 + k * 64 + t] = Ss[t];
}

// ---------------------------------------------------------------------------
// K7: epilogue  x = Minv * (alpha * A^T S - q)
// (kernel boundary after k_admm_p gives device-wide visibility of Sbuf)
// ---------------------------------------------------------------------------
__global__ __launch_bounds__(256) void k_final(
    const float* __restrict__ A, const float* __restrict__ q,
    const float* __restrict__ Mi, const float* __restrict__ Sbuf,
    float* __restrict__ xout) {
  int b = blockIdx.x, t = threadIdx.x;  // t = n index
  __shared__ float Ssh[512];
  __shared__ float uu[256];
  for (int i = t; i < 512; i += 256) Ssh[i] = Sbuf[(size_t)b * 512 + i];
  __syncthreads();
  const float* Ab = A + (size_t)b * 131072;
  float acc = 0.0f;
  for (int m = 0; m < 512; ++m) acc += Ab[(size_t)m * 256 + t] * Ssh[m];
  uu[t] = ALPHA_C * acc - q[(size_t)b * 256 + t];
  __syncthreads();
  const float* Mb = Mi + (size_t)b * 65536;
  float x = 0.0f;
  for (int kk = 0; kk < 256; ++kk) x += Mb[(size_t)kk * 256 + t] * uu[kk];
  xout[(size_t)b * 256 + t] = x;
}

// ---------------------------------------------------------------------------
extern "C" void kernel_launch(void* const* d_in, const int* in_sizes, int n_in,
                              void* d_out, int out_size, void* d_ws, size_t ws_size,
                              hipStream_t stream) {
  (void)in_sizes; (void)n_in; (void)out_size; (void)ws_size;
  const float* P = (const float*)d_in[0];
  const float* q = (const float*)d_in[1];
  const float* Av = (const float*)d_in[2];
  const float* lv = (const float*)d_in[3];
  const float* uv = (const float*)d_in[4];
  float* xout = (float*)d_out;

  float* ws = (float*)d_ws;
  float* At = ws;                       // 64*256*512 floats; dies after k_matvec_d
  float* F  = ws;                       // alias of At
  float* Mi = ws + 8388608;             // 64*256*256
  float* Mk = ws + 12582912;            // dies after k_invert
  float* G  = ws + 12582912;            // 64*512*512 (over dead Mk)
  float* hv = ws + 29360128;            // 64*256
  float* dv = ws + 29376512;            // 64*512
  float* wbuf = ws + 29409280;          // 2*64*512 double-buffered w
  float* Sbuf = ws + 29474816;          // 64*512
  int*   ctr  = (int*)(ws + 29507584);  // 64*32 ints (128B padded counters)

  k_transpose<<<dim3(8, 16, 64), dim3(32, 8), 0, stream>>>(Av, At);
  k_ntgemm<<<dim3(4, 64), 256, 0, stream>>>(At, At, Mk, 256, 256, 512,
                                            131072LL, 131072LL, 65536LL,
                                            RHO_C, P, 2);
  k_invert<<<64, 1024, 0, stream>>>(Mk, Mi);
  k_matvec_h<<<64, 256, 0, stream>>>(Mi, q, hv);
  k_matvec_d<<<64, 512, 0, stream>>>(At, hv, dv);
  k_ntgemm<<<dim3(8, 64), 256, 0, stream>>>(Av, Mi, F, 512, 256, 256,
                                            131072LL, 65536LL, 131072LL,
                                            1.0f, nullptr, 2);
  k_ntgemm<<<dim3(16, 64), 256, 0, stream>>>(F, Av, G, 512, 512, 256,
                                             131072LL, 131072LL, 262144LL,
                                             1.0f, nullptr, 4);
  k_zero<<<8, 256, 0, stream>>>(ctr, 2048);
  k_admm_p<<<512, 512, 0, stream>>>(G, dv, lv, uv, wbuf, ctr, Sbuf);
  k_final<<<64, 256, 0, stream>>>(Av, q, Mi, Sbuf, xout);
}